// Round 4
// baseline (369.309 us; speedup 1.0000x reference)
//
#include <hip/hip_runtime.h>
#include <hip/hip_bf16.h>

#define HDIM 128
#define H3   384
#define RDIM 20
#define NPB  16   // nodes per block (node MLP)
#define NPR  4    // nodes per reduce block
#define CHNK 16   // edges per MFMA chunk

typedef unsigned short u16;
typedef unsigned int   u32;
typedef __attribute__((ext_vector_type(8))) short short8v;  // 8 x bf16 bits
typedef __attribute__((ext_vector_type(4))) float f32x4;

__device__ __forceinline__ u16 f2bf(float f) {
    __hip_bfloat16 h = __float2bfloat16(f);   // RNE
    return *(u16*)&h;
}
__device__ __forceinline__ float bf2f(u16 u) {
    union { u32 i; float f; } x; x.i = (u32)u << 16; return x.f;
}
__device__ __forceinline__ float bflo(u32 u) {   // low bf16 of packed pair
    union { u32 i; float f; } x; x.i = u << 16; return x.f;
}
__device__ __forceinline__ float bfhi(u32 u) {   // high bf16 of packed pair
    union { u32 i; float f; } x; x.i = u & 0xffff0000u; return x.f;
}
__device__ __forceinline__ u32 pk(float lo, float hi) {
    return (u32)f2bf(lo) | ((u32)f2bf(hi) << 16);
}

// -------- Kernel 1: per-node MLP -> packed bf16 (PA,PB,PC); fuses v conversion --------
__global__ __launch_bounds__(128) void node_mlp_kernel(
    const float* __restrict__ s, const float* __restrict__ W1,
    const float* __restrict__ b1, const float* __restrict__ W2,
    const float* __restrict__ b2, const float* __restrict__ v,
    u32* __restrict__ PA, u32* __restrict__ PB, u32* __restrict__ PC, int N)
{
    __shared__ float sS[NPB][HDIM];
    __shared__ float sH[NPB][HDIM];
    const int t  = threadIdx.x;
    const int n0 = blockIdx.x * NPB;

    #pragma unroll
    for (int n = 0; n < NPB; ++n) {
        int node = n0 + n;
        sS[n][t] = (node < N) ? s[(size_t)node * HDIM + t] : 0.f;
    }
    __syncthreads();

    float acc[NPB];
    #pragma unroll
    for (int n = 0; n < NPB; ++n) acc[n] = 0.f;
    for (int k = 0; k < HDIM; ++k) {
        float w = W1[k * HDIM + t];
        #pragma unroll
        for (int n = 0; n < NPB; ++n) acc[n] += sS[n][k] * w;
    }
    float bb = b1[t];
    #pragma unroll
    for (int n = 0; n < NPB; ++n) {
        float z = acc[n] + bb;
        sH[n][t] = z / (1.f + __expf(-z));   // silu
    }
    __syncthreads();

    float a0[NPB], a1[NPB], a2[NPB];
    #pragma unroll
    for (int n = 0; n < NPB; ++n) { a0[n] = 0.f; a1[n] = 0.f; a2[n] = 0.f; }
    for (int k2 = 0; k2 < HDIM / 2; ++k2) {
        float2 hv[NPB];
        #pragma unroll
        for (int n = 0; n < NPB; ++n) hv[n] = ((const float2*)sH[n])[k2];
        #pragma unroll
        for (int kk = 0; kk < 2; ++kk) {
            int k = 2 * k2 + kk;
            float w0 = W2[k * H3 + t];
            float w1 = W2[k * H3 + t + 128];
            float w2 = W2[k * H3 + t + 256];
            #pragma unroll
            for (int n = 0; n < NPB; ++n) {
                float h = kk ? hv[n].y : hv[n].x;
                a0[n] += h * w0;
                a1[n] += h * w1;
                a2[n] += h * w2;
            }
        }
    }
    float c0 = b2[t], c1 = b2[t + 128], c2 = b2[t + 256];
    #pragma unroll
    for (int n = 0; n < NPB; ++n) {
        int node = n0 + n;
        if (node < N) {
            size_t vb = (size_t)node * H3;
            float vx = v[vb + t], vy = v[vb + 128 + t], vz = v[vb + 256 + t];
            size_t pb = (size_t)node * HDIM + t;
            PA[pb] = pk(a0[n] + c0, a1[n] + c1);   // (pss, psv)
            PB[pb] = pk(a2[n] + c2, vx);           // (pvv, vx)
            PC[pb] = pk(vy, vz);                   // (vy, vz)
        }
    }
}

// -------- CSR build --------
__global__ void hist_kernel(const int* __restrict__ eidx, int* __restrict__ counts, int E)
{
    int e = blockIdx.x * 256 + threadIdx.x;
    if (e < E) atomicAdd(&counts[eidx[e]], 1);
}

__global__ __launch_bounds__(1024) void scan_kernel(
    const int* __restrict__ counts, int* __restrict__ rstart,
    int* __restrict__ cursor, int N)
{
    __shared__ int part[1024];
    const int t = threadIdx.x;
    const int C = 20;
    int loc[C];
    int s = 0;
    #pragma unroll
    for (int q = 0; q < C; ++q) {
        int idx = t * C + q;
        int c = (idx < N) ? counts[idx] : 0;
        loc[q] = s; s += c;
    }
    part[t] = s;
    __syncthreads();
    for (int off = 1; off < 1024; off <<= 1) {
        int vv = (t >= off) ? part[t - off] : 0;
        __syncthreads();
        part[t] += vv;
        __syncthreads();
    }
    int boff = (t > 0) ? part[t - 1] : 0;
    #pragma unroll
    for (int q = 0; q < C; ++q) {
        int idx = t * C + q;
        if (idx < N) {
            int st = boff + loc[q];
            rstart[idx] = st;
            cursor[idx] = st;
        }
    }
    if (t == 1023) rstart[N] = part[1023];
}

__global__ void scatter_kernel(const int* __restrict__ eidx, int* __restrict__ cursor,
                               int* __restrict__ eord, int E)
{
    int e = blockIdx.x * 256 + threadIdx.x;
    if (e < E) {
        int i = eidx[e];
        int pos = atomicAdd(&cursor[i], 1);
        eord[pos] = e;
    }
}

// -------- Kernel 2: node-centric gather-reduce with in-kernel MFMA for rbf@Wr --------
__global__ __launch_bounds__(128) void reduce_kernel(
    const int* __restrict__ rstart, const int* __restrict__ eord,
    const float* __restrict__ rbf, const float* __restrict__ cutoff,
    const float* __restrict__ evec, const float* __restrict__ Wr,
    const float* __restrict__ br, const u32* __restrict__ PA,
    const u32* __restrict__ PB, const u32* __restrict__ PC,
    const int* __restrict__ eidx, float* __restrict__ ds,
    float* __restrict__ dv, int E, int N)
{
    const int t    = threadIdx.x;
    const int lane = t & 63;
    const int wave = t >> 6;
    const int g    = lane >> 4;   // k-group within fragment
    const int m    = lane & 15;   // row (edge) / col within tile

    // B fragments: Wr in bf16, 12 column-tiles per wave, constant all kernel.
    // Lane holds B[k = 8*g + j][col = wave*192 + n*16 + m]; k >= RDIM zeroed.
    short8v bfrag[12];
    #pragma unroll
    for (int n = 0; n < 12; ++n) {
        int col = wave * 192 + n * 16 + m;
        short8v f;
        #pragma unroll
        for (int j = 0; j < 8; ++j) {
            int k = 8 * g + j;
            float val = (k < RDIM) ? Wr[k * H3 + col] : 0.f;
            f[j] = (short)f2bf(val);
        }
        bfrag[n] = f;
    }
    float br0 = br[t], br1 = br[t + 128], br2 = br[t + 256];

    __shared__ int   sE[CHNK], sJ[CHNK];
    __shared__ float sCut[CHNK], sVx[CHNK], sVy[CHNK], sVz[CHNK];
    __shared__ u16   Wl[CHNK][H3];   // bf16 W values for current chunk

    for (int nn = 0; nn < NPR; ++nn) {
        int node = blockIdx.x * NPR + nn;
        if (node >= N) break;
        int beg = rstart[node], end = rstart[node + 1];
        float accs = 0.f, accx = 0.f, accy = 0.f, accz = 0.f;

        for (int c0 = beg; c0 < end; c0 += CHNK) {
            int cnt = min(CHNK, end - c0);
            __syncthreads();   // previous chunk fully consumed
            if (t < CHNK) {
                int e = eord[c0 + ((t < cnt) ? t : 0)];   // pad with a valid edge
                sE[t]   = e;
                sJ[t]   = eidx[E + e];
                sCut[t] = cutoff[e];
                sVx[t]  = evec[3 * e];
                sVy[t]  = evec[3 * e + 1];
                sVz[t]  = evec[3 * e + 2];
            }
            __syncthreads();

            // A fragment: lane holds rbf[edge m][k = 8*g + j] as bf16, k>=RDIM zero
            short8v af;
            if (g == 3) {
                #pragma unroll
                for (int j = 0; j < 8; ++j) af[j] = 0;
            } else {
                const float* rrow = rbf + (size_t)sE[m] * RDIM;
                if (g < 2) {
                    float4 r0 = *(const float4*)(rrow + 8 * g);
                    float4 r1 = *(const float4*)(rrow + 8 * g + 4);
                    af[0] = (short)f2bf(r0.x); af[1] = (short)f2bf(r0.y);
                    af[2] = (short)f2bf(r0.z); af[3] = (short)f2bf(r0.w);
                    af[4] = (short)f2bf(r1.x); af[5] = (short)f2bf(r1.y);
                    af[6] = (short)f2bf(r1.z); af[7] = (short)f2bf(r1.w);
                } else {  // g == 2: k = 16..19 valid, 20..23 zero
                    float4 r0 = *(const float4*)(rrow + 16);
                    af[0] = (short)f2bf(r0.x); af[1] = (short)f2bf(r0.y);
                    af[2] = (short)f2bf(r0.z); af[3] = (short)f2bf(r0.w);
                    af[4] = 0; af[5] = 0; af[6] = 0; af[7] = 0;
                }
            }

            // 12 MFMAs -> W chunk -> LDS (bf16). C layout: col=lane&15, row=4*(lane>>4)+r
            #pragma unroll
            for (int n = 0; n < 12; ++n) {
                f32x4 c = {0.f, 0.f, 0.f, 0.f};
                c = __builtin_amdgcn_mfma_f32_16x16x32_bf16(af, bfrag[n], c, 0, 0, 0);
                int col = wave * 192 + n * 16 + m;
                #pragma unroll
                for (int r = 0; r < 4; ++r)
                    Wl[4 * g + r][col] = f2bf(c[r]);
            }
            __syncthreads();

            // edge loop: gathers pipelined one ahead
            u32 ca, cb, cc;
            {
                size_t pj = (size_t)sJ[0] * HDIM + t;
                ca = PA[pj]; cb = PB[pj]; cc = PC[pj];
            }
            for (int q = 0; q < cnt; ++q) {
                u32 na = 0, nb = 0, nc = 0;
                if (q + 1 < cnt) {
                    size_t pj = (size_t)sJ[q + 1] * HDIM + t;
                    na = PA[pj]; nb = PB[pj]; nc = PC[pj];
                }
                float w0 = bf2f(Wl[q][t]);
                float w1 = bf2f(Wl[q][t + 128]);
                float w2 = bf2f(Wl[q][t + 256]);
                float cu = sCut[q];
                float ex = sVx[q], ey = sVy[q], ez = sVz[q];
                float pss = bflo(ca), psv = bfhi(ca);
                float pvv = bflo(cb), vx  = bfhi(cb);
                float vy  = bflo(cc), vz  = bfhi(cc);
                float xss = (w0 + br0) * cu * pss;
                float xsv = (w1 + br1) * cu * psv;
                float xvv = (w2 + br2) * cu * pvv;
                float inner = vx * ex + vy * ey + vz * ez;
                float coef  = xsv + inner * xvv;
                accs += xss;
                accx += coef * ex;
                accy += coef * ey;
                accz += coef * ez;
                ca = na; cb = nb; cc = nc;
            }
        }

        ds[(size_t)node * HDIM + t] = accs;
        size_t dvi = (size_t)node * H3;
        dv[dvi + t]       = accx;
        dv[dvi + 128 + t] = accy;
        dv[dvi + 256 + t] = accz;
    }
}

extern "C" void kernel_launch(void* const* d_in, const int* in_sizes, int n_in,
                              void* d_out, int out_size, void* d_ws, size_t ws_size,
                              hipStream_t stream)
{
    const float* s    = (const float*)d_in[0];
    const float* v    = (const float*)d_in[1];
    const float* rbf  = (const float*)d_in[2];
    const float* cut  = (const float*)d_in[3];
    const float* evec = (const float*)d_in[4];
    const float* W1   = (const float*)d_in[5];
    const float* b1   = (const float*)d_in[6];
    const float* W2   = (const float*)d_in[7];
    const float* b2   = (const float*)d_in[8];
    const float* Wr   = (const float*)d_in[9];
    const float* br   = (const float*)d_in[10];
    const int*   eidx = (const int*)d_in[11];

    const int N = in_sizes[0] / HDIM;   // 20000
    const int E = in_sizes[3];          // 400000

    float* out = (float*)d_out;
    float* ds  = out;                      // [N, H]
    float* dv  = out + (size_t)N * HDIM;   // [N, 3, H]

    // workspace layout (256B aligned chunks)
    char* w = (char*)d_ws;
    u32* PA = (u32*)w;                     w += ((size_t)N * HDIM * 4 + 255) / 256 * 256;
    u32* PB = (u32*)w;                     w += ((size_t)N * HDIM * 4 + 255) / 256 * 256;
    u32* PC = (u32*)w;                     w += ((size_t)N * HDIM * 4 + 255) / 256 * 256;
    int* counts = (int*)w;                 w += ((size_t)N * 4 + 255) / 256 * 256;
    int* rstart = (int*)w;                 w += ((size_t)(N + 1) * 4 + 255) / 256 * 256;
    int* cursor = (int*)w;                 w += ((size_t)N * 4 + 255) / 256 * 256;
    int* eord   = (int*)w;

    hipMemsetAsync(counts, 0, (size_t)N * sizeof(int), stream);

    node_mlp_kernel<<<(N + NPB - 1) / NPB, 128, 0, stream>>>(s, W1, b1, W2, b2, v,
                                                             PA, PB, PC, N);
    hist_kernel<<<(E + 255) / 256, 256, 0, stream>>>(eidx, counts, E);
    scan_kernel<<<1, 1024, 0, stream>>>(counts, rstart, cursor, N);
    scatter_kernel<<<(E + 255) / 256, 256, 0, stream>>>(eidx, cursor, eord, E);
    reduce_kernel<<<(N + NPR - 1) / NPR, 128, 0, stream>>>(rstart, eord, rbf, cut, evec,
                                                           Wr, br, PA, PB, PC, eidx,
                                                           ds, dv, E, N);
}

// Round 6
// 346.700 us; speedup vs baseline: 1.0652x; 1.0652x over previous
//
#include <hip/hip_runtime.h>
#include <hip/hip_bf16.h>

#define HDIM 128
#define H3   384
#define RDIM 20
#define NPB  16   // nodes per block (node MLP)
#define NPR  4    // nodes per reduce block
#define CHNK 32   // edge chunk staged in LDS
#define RBLK 512  // reduce block size (4 substreams x 128 channels)

typedef unsigned short u16;
typedef unsigned int   u32;

__device__ __forceinline__ u16 f2bf(float f) {
    __hip_bfloat16 h = __float2bfloat16(f);   // RNE
    return *(u16*)&h;
}
__device__ __forceinline__ float bflo(u32 u) {
    union { u32 i; float f; } x; x.i = u << 16; return x.f;
}
__device__ __forceinline__ float bfhi(u32 u) {
    union { u32 i; float f; } x; x.i = u & 0xffff0000u; return x.f;
}
__device__ __forceinline__ u32 pk(float lo, float hi) {
    return (u32)f2bf(lo) | ((u32)f2bf(hi) << 16);
}

// -------- Kernel 1: per-node MLP -> packed bf16 P3[node][3][128]; fuses v conv --------
__global__ __launch_bounds__(128) void node_mlp_kernel(
    const float* __restrict__ s, const float* __restrict__ W1,
    const float* __restrict__ b1, const float* __restrict__ W2,
    const float* __restrict__ b2, const float* __restrict__ v,
    u32* __restrict__ P3, int N)
{
    __shared__ float sS[NPB][HDIM];
    __shared__ float sH[NPB][HDIM];
    const int t  = threadIdx.x;
    const int n0 = blockIdx.x * NPB;

    #pragma unroll
    for (int n = 0; n < NPB; ++n) {
        int node = n0 + n;
        sS[n][t] = (node < N) ? s[(size_t)node * HDIM + t] : 0.f;
    }
    __syncthreads();

    float acc[NPB];
    #pragma unroll
    for (int n = 0; n < NPB; ++n) acc[n] = 0.f;
    for (int k = 0; k < HDIM; ++k) {
        float w = W1[k * HDIM + t];
        #pragma unroll
        for (int n = 0; n < NPB; ++n) acc[n] += sS[n][k] * w;
    }
    float bb = b1[t];
    #pragma unroll
    for (int n = 0; n < NPB; ++n) {
        float z = acc[n] + bb;
        sH[n][t] = z / (1.f + __expf(-z));   // silu
    }
    __syncthreads();

    float a0[NPB], a1[NPB], a2[NPB];
    #pragma unroll
    for (int n = 0; n < NPB; ++n) { a0[n] = 0.f; a1[n] = 0.f; a2[n] = 0.f; }
    for (int k2 = 0; k2 < HDIM / 2; ++k2) {
        float2 hv[NPB];
        #pragma unroll
        for (int n = 0; n < NPB; ++n) hv[n] = ((const float2*)sH[n])[k2];
        #pragma unroll
        for (int kk = 0; kk < 2; ++kk) {
            int k = 2 * k2 + kk;
            float w0 = W2[k * H3 + t];
            float w1 = W2[k * H3 + t + 128];
            float w2 = W2[k * H3 + t + 256];
            #pragma unroll
            for (int n = 0; n < NPB; ++n) {
                float h = kk ? hv[n].y : hv[n].x;
                a0[n] += h * w0;
                a1[n] += h * w1;
                a2[n] += h * w2;
            }
        }
    }
    float c0 = b2[t], c1 = b2[t + 128], c2 = b2[t + 256];
    #pragma unroll
    for (int n = 0; n < NPB; ++n) {
        int node = n0 + n;
        if (node < N) {
            size_t vb = (size_t)node * H3;
            float vx = v[vb + t], vy = v[vb + 128 + t], vz = v[vb + 256 + t];
            size_t pb = (size_t)node * H3 + t;
            P3[pb]       = pk(a0[n] + c0, a1[n] + c1);   // (pss, psv)
            P3[pb + 128] = pk(a2[n] + c2, vx);           // (pvv, vx)
            P3[pb + 256] = pk(vy, vz);                   // (vy, vz)
        }
    }
}

// -------- CSR build --------
__global__ void hist_kernel(const int* __restrict__ eidx, int* __restrict__ counts, int E)
{
    int e = blockIdx.x * 256 + threadIdx.x;
    if (e < E) atomicAdd(&counts[eidx[e]], 1);
}

__global__ __launch_bounds__(1024) void scan_kernel(
    const int* __restrict__ counts, int* __restrict__ rstart,
    int* __restrict__ cursor, int N)
{
    __shared__ int part[1024];
    const int t = threadIdx.x;
    const int C = 20;
    int loc[C];
    int s = 0;
    #pragma unroll
    for (int q = 0; q < C; ++q) {
        int idx = t * C + q;
        int c = (idx < N) ? counts[idx] : 0;
        loc[q] = s; s += c;
    }
    part[t] = s;
    __syncthreads();
    for (int off = 1; off < 1024; off <<= 1) {
        int vv = (t >= off) ? part[t - off] : 0;
        __syncthreads();
        part[t] += vv;
        __syncthreads();
    }
    int boff = (t > 0) ? part[t - 1] : 0;
    #pragma unroll
    for (int q = 0; q < C; ++q) {
        int idx = t * C + q;
        if (idx < N) {
            int st = boff + loc[q];
            rstart[idx] = st;
            cursor[idx] = st;
        }
    }
    if (t == 1023) rstart[N] = part[1023];
}

__global__ void scatter_kernel(const int* __restrict__ eidx, int* __restrict__ cursor,
                               int* __restrict__ eord, int E)
{
    int e = blockIdx.x * 256 + threadIdx.x;
    if (e < E) {
        int i = eidx[e];
        int pos = atomicAdd(&cursor[i], 1);
        eord[pos] = e;
    }
}

// -------- Kernel 2: node-centric gather-reduce, 4 edge-substreams per node --------
__global__ __launch_bounds__(RBLK) void reduce_kernel(
    const int* __restrict__ rstart, const int* __restrict__ eord,
    const float* __restrict__ rbf, const float* __restrict__ cutoff,
    const float* __restrict__ evec, const float* __restrict__ Wr,
    const float* __restrict__ br, const u32* __restrict__ P3,
    const int* __restrict__ eidx, float* __restrict__ ds,
    float* __restrict__ dv, int E, int N)
{
    const int t  = threadIdx.x;
    const int ch = t & (HDIM - 1);
    const int u  = t >> 7;          // substream 0..3

    // Wr columns for this channel, in registers for the whole kernel
    float wr0[RDIM], wr1[RDIM], wr2[RDIM];
    #pragma unroll
    for (int k = 0; k < RDIM; ++k) {
        wr0[k] = Wr[k * H3 + ch];
        wr1[k] = Wr[k * H3 + ch + 128];
        wr2[k] = Wr[k * H3 + ch + 256];
    }
    const float br0 = br[ch], br1 = br[ch + 128], br2 = br[ch + 256];

    __shared__ int   sJoff[CHNK];
    __shared__ float sCut[CHNK], sVx[CHNK], sVy[CHNK], sVz[CHNK];
    __shared__ __attribute__((aligned(16))) float sRbf[CHNK][RDIM];
    __shared__ float sRed[3][4][HDIM];

    for (int nn = 0; nn < NPR; ++nn) {
        int node = blockIdx.x * NPR + nn;
        if (node >= N) break;
        int beg = rstart[node], end = rstart[node + 1];
        float accs = 0.f, accx = 0.f, accy = 0.f, accz = 0.f;

        for (int c0 = beg; c0 < end; c0 += CHNK) {
            int cnt = min(CHNK, end - c0);
            __syncthreads();   // previous chunk fully consumed
            if (t < cnt) {
                int e = eord[c0 + t];
                sJoff[t] = eidx[E + e] * H3;
                sCut[t]  = cutoff[e];
                sVx[t]   = evec[3 * e];
                sVy[t]   = evec[3 * e + 1];
                sVz[t]   = evec[3 * e + 2];
            }
            for (int x = t; x < cnt * RDIM; x += RBLK) {
                int n = x / RDIM, k = x - n * RDIM;
                int e = eord[c0 + n];      // L2-hot re-read, avoids a 3rd barrier
                sRbf[n][k] = rbf[(size_t)e * RDIM + k];
            }
            __syncthreads();

            // substream u handles q = u, u+4, u+8, ...; depth-1 gather pipeline
            int q = u;
            u32 ca = 0, cb = 0, cc = 0;
            if (q < cnt) {
                int idx = sJoff[q] + ch;
                ca = P3[idx]; cb = P3[idx + 128]; cc = P3[idx + 256];
            }
            for (; q < cnt; q += 4) {
                int qn = q + 4;
                u32 na = 0, nb = 0, nc = 0;
                if (qn < cnt) {
                    int idx = sJoff[qn] + ch;
                    na = P3[idx]; nb = P3[idx + 128]; nc = P3[idx + 256];
                }
                const float4* r4 = (const float4*)sRbf[q];
                float w0 = 0.f, w1 = 0.f, w2 = 0.f;
                #pragma unroll
                for (int k4 = 0; k4 < 5; ++k4) {
                    float4 r = r4[k4];
                    w0 += r.x * wr0[4*k4] + r.y * wr0[4*k4+1] + r.z * wr0[4*k4+2] + r.w * wr0[4*k4+3];
                    w1 += r.x * wr1[4*k4] + r.y * wr1[4*k4+1] + r.z * wr1[4*k4+2] + r.w * wr1[4*k4+3];
                    w2 += r.x * wr2[4*k4] + r.y * wr2[4*k4+1] + r.z * wr2[4*k4+2] + r.w * wr2[4*k4+3];
                }
                float cu = sCut[q];
                float ex = sVx[q], ey = sVy[q], ez = sVz[q];
                float pss = bflo(ca), psv = bfhi(ca);
                float pvv = bflo(cb), vx  = bfhi(cb);
                float vy  = bflo(cc), vz  = bfhi(cc);
                float xss = (w0 + br0) * cu * pss;
                float xsv = (w1 + br1) * cu * psv;
                float xvv = (w2 + br2) * cu * pvv;
                float inner = vx * ex + vy * ey + vz * ez;
                float coef  = xsv + inner * xvv;
                accs += xss;
                accx += coef * ex;
                accy += coef * ey;
                accz += coef * ez;
                ca = na; cb = nb; cc = nc;
            }
        }

        // merge 4 substream partials
        __syncthreads();
        if (u > 0) {
            sRed[u - 1][0][ch] = accs;
            sRed[u - 1][1][ch] = accx;
            sRed[u - 1][2][ch] = accy;
            sRed[u - 1][3][ch] = accz;
        }
        __syncthreads();
        if (u == 0) {
            accs += sRed[0][0][ch] + sRed[1][0][ch] + sRed[2][0][ch];
            accx += sRed[0][1][ch] + sRed[1][1][ch] + sRed[2][1][ch];
            accy += sRed[0][2][ch] + sRed[1][2][ch] + sRed[2][2][ch];
            accz += sRed[0][3][ch] + sRed[1][3][ch] + sRed[2][3][ch];
            ds[(size_t)node * HDIM + ch] = accs;
            size_t dvi = (size_t)node * H3;
            dv[dvi + ch]       = accx;
            dv[dvi + 128 + ch] = accy;
            dv[dvi + 256 + ch] = accz;
        }
    }
}

extern "C" void kernel_launch(void* const* d_in, const int* in_sizes, int n_in,
                              void* d_out, int out_size, void* d_ws, size_t ws_size,
                              hipStream_t stream)
{
    const float* s    = (const float*)d_in[0];
    const float* v    = (const float*)d_in[1];
    const float* rbf  = (const float*)d_in[2];
    const float* cut  = (const float*)d_in[3];
    const float* evec = (const float*)d_in[4];
    const float* W1   = (const float*)d_in[5];
    const float* b1   = (const float*)d_in[6];
    const float* W2   = (const float*)d_in[7];
    const float* b2   = (const float*)d_in[8];
    const float* Wr   = (const float*)d_in[9];
    const float* br   = (const float*)d_in[10];
    const int*   eidx = (const int*)d_in[11];

    const int N = in_sizes[0] / HDIM;   // 20000
    const int E = in_sizes[3];          // 400000

    float* out = (float*)d_out;
    float* ds  = out;                      // [N, H]
    float* dv  = out + (size_t)N * HDIM;   // [N, 3, H]

    // workspace layout (256B aligned chunks)
    char* w = (char*)d_ws;
    u32* P3 = (u32*)w;                     w += ((size_t)N * H3 * 4 + 255) / 256 * 256;
    int* counts = (int*)w;                 w += ((size_t)N * 4 + 255) / 256 * 256;
    int* rstart = (int*)w;                 w += ((size_t)(N + 1) * 4 + 255) / 256 * 256;
    int* cursor = (int*)w;                 w += ((size_t)N * 4 + 255) / 256 * 256;
    int* eord   = (int*)w;

    hipMemsetAsync(counts, 0, (size_t)N * sizeof(int), stream);

    node_mlp_kernel<<<(N + NPB - 1) / NPB, 128, 0, stream>>>(s, W1, b1, W2, b2, v, P3, N);
    hist_kernel<<<(E + 255) / 256, 256, 0, stream>>>(eidx, counts, E);
    scan_kernel<<<1, 1024, 0, stream>>>(counts, rstart, cursor, N);
    scatter_kernel<<<(E + 255) / 256, 256, 0, stream>>>(eidx, cursor, eord, E);
    reduce_kernel<<<(N + NPR - 1) / NPR, RBLK, 0, stream>>>(rstart, eord, rbf, cut, evec,
                                                            Wr, br, P3, eidx, ds, dv, E, N);
}

// Round 7
// 319.755 us; speedup vs baseline: 1.1550x; 1.0843x over previous
//
#include <hip/hip_runtime.h>
#include <hip/hip_bf16.h>

#define HDIM 128
#define H3   384
#define RDIM 20
#define NPB  16   // nodes per block (node MLP)
#define EPB  64   // edges per block (edge stream kernel)

typedef unsigned short u16;
typedef unsigned int   u32;

__device__ __forceinline__ u16 f2bf(float f) {
    __hip_bfloat16 h = __float2bfloat16(f);   // RNE
    return *(u16*)&h;
}
__device__ __forceinline__ float bflo(u32 u) {
    union { u32 i; float f; } x; x.i = u << 16; return x.f;
}
__device__ __forceinline__ float bfhi(u32 u) {
    union { u32 i; float f; } x; x.i = u & 0xffff0000u; return x.f;
}
__device__ __forceinline__ u32 pk(float lo, float hi) {
    return (u32)f2bf(lo) | ((u32)f2bf(hi) << 16);
}

// -------- Kernel 1: per-node MLP -> packed bf16 P3[node][3][128]; fuses v conv --------
__global__ __launch_bounds__(128) void node_mlp_kernel(
    const float* __restrict__ s, const float* __restrict__ W1,
    const float* __restrict__ b1, const float* __restrict__ W2,
    const float* __restrict__ b2, const float* __restrict__ v,
    u32* __restrict__ P3, int N)
{
    __shared__ float sS[NPB][HDIM];
    __shared__ float sH[NPB][HDIM];
    const int t  = threadIdx.x;
    const int n0 = blockIdx.x * NPB;

    #pragma unroll
    for (int n = 0; n < NPB; ++n) {
        int node = n0 + n;
        sS[n][t] = (node < N) ? s[(size_t)node * HDIM + t] : 0.f;
    }
    __syncthreads();

    float acc[NPB];
    #pragma unroll
    for (int n = 0; n < NPB; ++n) acc[n] = 0.f;
    for (int k = 0; k < HDIM; ++k) {
        float w = W1[k * HDIM + t];
        #pragma unroll
        for (int n = 0; n < NPB; ++n) acc[n] += sS[n][k] * w;
    }
    float bb = b1[t];
    #pragma unroll
    for (int n = 0; n < NPB; ++n) {
        float z = acc[n] + bb;
        sH[n][t] = z / (1.f + __expf(-z));   // silu
    }
    __syncthreads();

    float a0[NPB], a1[NPB], a2[NPB];
    #pragma unroll
    for (int n = 0; n < NPB; ++n) { a0[n] = 0.f; a1[n] = 0.f; a2[n] = 0.f; }
    for (int k2 = 0; k2 < HDIM / 2; ++k2) {
        float2 hv[NPB];
        #pragma unroll
        for (int n = 0; n < NPB; ++n) hv[n] = ((const float2*)sH[n])[k2];
        #pragma unroll
        for (int kk = 0; kk < 2; ++kk) {
            int k = 2 * k2 + kk;
            float w0 = W2[k * H3 + t];
            float w1 = W2[k * H3 + t + 128];
            float w2 = W2[k * H3 + t + 256];
            #pragma unroll
            for (int n = 0; n < NPB; ++n) {
                float h = kk ? hv[n].y : hv[n].x;
                a0[n] += h * w0;
                a1[n] += h * w1;
                a2[n] += h * w2;
            }
        }
    }
    float c0 = b2[t], c1 = b2[t + 128], c2 = b2[t + 256];
    #pragma unroll
    for (int n = 0; n < NPB; ++n) {
        int node = n0 + n;
        if (node < N) {
            size_t vb = (size_t)node * H3;
            float vx = v[vb + t], vy = v[vb + 128 + t], vz = v[vb + 256 + t];
            size_t pb = (size_t)node * H3 + t;
            P3[pb]       = pk(a0[n] + c0, a1[n] + c1);   // (pss, psv)
            P3[pb + 128] = pk(a2[n] + c2, vx);           // (pvv, vx)
            P3[pb + 256] = pk(vy, vz);                   // (vy, vz)
        }
    }
}

// -------- CSR build (sort edges by destination) --------
__global__ void hist_kernel(const int* __restrict__ eidx, int* __restrict__ counts, int E)
{
    int e = blockIdx.x * 256 + threadIdx.x;
    if (e < E) atomicAdd(&counts[eidx[e]], 1);
}

__global__ __launch_bounds__(1024) void scan_kernel(
    const int* __restrict__ counts, int* __restrict__ rstart,
    int* __restrict__ cursor, int N)
{
    __shared__ int part[1024];
    const int t = threadIdx.x;
    const int C = 20;
    int loc[C];
    int s = 0;
    #pragma unroll
    for (int q = 0; q < C; ++q) {
        int idx = t * C + q;
        int c = (idx < N) ? counts[idx] : 0;
        loc[q] = s; s += c;
    }
    part[t] = s;
    __syncthreads();
    for (int off = 1; off < 1024; off <<= 1) {
        int vv = (t >= off) ? part[t - off] : 0;
        __syncthreads();
        part[t] += vv;
        __syncthreads();
    }
    int boff = (t > 0) ? part[t - 1] : 0;
    #pragma unroll
    for (int q = 0; q < C; ++q) {
        int idx = t * C + q;
        if (idx < N) {
            int st = boff + loc[q];
            rstart[idx] = st;
            cursor[idx] = st;
        }
    }
    if (t == 1023) rstart[N] = part[1023];
}

__global__ void scatter_kernel(const int* __restrict__ eidx, int* __restrict__ cursor,
                               int* __restrict__ eord, int E)
{
    int e = blockIdx.x * 256 + threadIdx.x;
    if (e < E) {
        int i = eidx[e];
        int pos = atomicAdd(&cursor[i], 1);
        eord[pos] = e;
    }
}

// -------- Kernel 2: edge-centric streaming over destination-sorted edges --------
// Block takes EPB consecutive eord entries; register-accumulates over runs of
// equal destination; flushes one atomicAdd set per run (~4 runs/block).
__global__ __launch_bounds__(128, 4) void edge_stream_kernel(
    const int* __restrict__ eord, const int* __restrict__ eidx,
    const float* __restrict__ rbf, const float* __restrict__ cutoff,
    const float* __restrict__ evec, const float* __restrict__ Wr,
    const float* __restrict__ br, const u32* __restrict__ P3,
    float* __restrict__ ds, float* __restrict__ dv, int E)
{
    const int t    = threadIdx.x;
    const int base = blockIdx.x * EPB;
    const int cnt  = min(EPB, E - base);

    // Wr columns for this thread's 3 output columns — MUST live in VGPRs.
    // __launch_bounds__(128,4) caps VGPR at 128 so the 60 values fit.
    float wr0[RDIM], wr1[RDIM], wr2[RDIM];
    #pragma unroll
    for (int k = 0; k < RDIM; ++k) {
        wr0[k] = Wr[k * H3 + t];
        wr1[k] = Wr[k * H3 + t + 128];
        wr2[k] = Wr[k * H3 + t + 256];
    }
    const float br0 = br[t], br1 = br[t + 128], br2 = br[t + 256];

    __shared__ int   sI[EPB], sJ[EPB];
    __shared__ float sCut[EPB], sVx[EPB], sVy[EPB], sVz[EPB];
    __shared__ __attribute__((aligned(16))) float sRbf[EPB][RDIM];

    if (t < cnt) {
        int e   = eord[base + t];
        sI[t]   = eidx[e];
        sJ[t]   = eidx[E + e] * H3;
        sCut[t] = cutoff[e];
        sVx[t]  = evec[3 * e];
        sVy[t]  = evec[3 * e + 1];
        sVz[t]  = evec[3 * e + 2];
    }
    for (int x = t; x < cnt * RDIM; x += 128) {
        int n = x / RDIM, k = x - n * RDIM;
        int e = eord[base + n];            // L1/L2-hot re-read
        sRbf[n][k] = rbf[(size_t)e * RDIM + k];
    }
    __syncthreads();

    // depth-1 prefetch of the 3 packed gather words
    u32 ca, cb, cc;
    {
        int idx = sJ[0] + t;
        ca = P3[idx]; cb = P3[idx + 128]; cc = P3[idx + 256];
    }
    int   cur  = sI[0];
    float accs = 0.f, accx = 0.f, accy = 0.f, accz = 0.f;

    for (int q = 0; q < cnt; ++q) {
        u32 na = 0, nb = 0, nc = 0;
        if (q + 1 < cnt) {
            int idx = sJ[q + 1] + t;
            na = P3[idx]; nb = P3[idx + 128]; nc = P3[idx + 256];
        }
        int iq = sI[q];                    // uniform across block
        if (iq != cur) {                   // run boundary: flush (uniform branch)
            atomicAdd(&ds[(size_t)cur * HDIM + t], accs);
            size_t dvi = (size_t)cur * H3;
            atomicAdd(&dv[dvi + t],       accx);
            atomicAdd(&dv[dvi + 128 + t], accy);
            atomicAdd(&dv[dvi + 256 + t], accz);
            accs = accx = accy = accz = 0.f;
            cur = iq;
        }
        const float4* r4 = (const float4*)sRbf[q];
        float w0 = 0.f, w1 = 0.f, w2 = 0.f;
        #pragma unroll
        for (int k4 = 0; k4 < 5; ++k4) {
            float4 r = r4[k4];
            w0 += r.x * wr0[4*k4] + r.y * wr0[4*k4+1] + r.z * wr0[4*k4+2] + r.w * wr0[4*k4+3];
            w1 += r.x * wr1[4*k4] + r.y * wr1[4*k4+1] + r.z * wr1[4*k4+2] + r.w * wr1[4*k4+3];
            w2 += r.x * wr2[4*k4] + r.y * wr2[4*k4+1] + r.z * wr2[4*k4+2] + r.w * wr2[4*k4+3];
        }
        float cu = sCut[q];
        float ex = sVx[q], ey = sVy[q], ez = sVz[q];
        float pss = bflo(ca), psv = bfhi(ca);
        float pvv = bflo(cb), vx  = bfhi(cb);
        float vy  = bflo(cc), vz  = bfhi(cc);
        float xss = (w0 + br0) * cu * pss;
        float xsv = (w1 + br1) * cu * psv;
        float xvv = (w2 + br2) * cu * pvv;
        float inner = vx * ex + vy * ey + vz * ez;
        float coef  = xsv + inner * xvv;
        accs += xss;
        accx += coef * ex;
        accy += coef * ey;
        accz += coef * ez;
        ca = na; cb = nb; cc = nc;
    }
    // final flush
    atomicAdd(&ds[(size_t)cur * HDIM + t], accs);
    size_t dvi = (size_t)cur * H3;
    atomicAdd(&dv[dvi + t],       accx);
    atomicAdd(&dv[dvi + 128 + t], accy);
    atomicAdd(&dv[dvi + 256 + t], accz);
}

extern "C" void kernel_launch(void* const* d_in, const int* in_sizes, int n_in,
                              void* d_out, int out_size, void* d_ws, size_t ws_size,
                              hipStream_t stream)
{
    const float* s    = (const float*)d_in[0];
    const float* v    = (const float*)d_in[1];
    const float* rbf  = (const float*)d_in[2];
    const float* cut  = (const float*)d_in[3];
    const float* evec = (const float*)d_in[4];
    const float* W1   = (const float*)d_in[5];
    const float* b1   = (const float*)d_in[6];
    const float* W2   = (const float*)d_in[7];
    const float* b2   = (const float*)d_in[8];
    const float* Wr   = (const float*)d_in[9];
    const float* br   = (const float*)d_in[10];
    const int*   eidx = (const int*)d_in[11];

    const int N = in_sizes[0] / HDIM;   // 20000
    const int E = in_sizes[3];          // 400000

    float* out = (float*)d_out;
    float* ds  = out;                      // [N, H]
    float* dv  = out + (size_t)N * HDIM;   // [N, 3, H]

    // workspace layout (256B aligned chunks)
    char* w = (char*)d_ws;
    u32* P3 = (u32*)w;                     w += ((size_t)N * H3 * 4 + 255) / 256 * 256;
    int* counts = (int*)w;                 w += ((size_t)N * 4 + 255) / 256 * 256;
    int* rstart = (int*)w;                 w += ((size_t)(N + 1) * 4 + 255) / 256 * 256;
    int* cursor = (int*)w;                 w += ((size_t)N * 4 + 255) / 256 * 256;
    int* eord   = (int*)w;

    hipMemsetAsync(d_out, 0, (size_t)out_size * sizeof(float), stream);
    hipMemsetAsync(counts, 0, (size_t)N * sizeof(int), stream);

    node_mlp_kernel<<<(N + NPB - 1) / NPB, 128, 0, stream>>>(s, W1, b1, W2, b2, v, P3, N);
    hist_kernel<<<(E + 255) / 256, 256, 0, stream>>>(eidx, counts, E);
    scan_kernel<<<1, 1024, 0, stream>>>(counts, rstart, cursor, N);
    scatter_kernel<<<(E + 255) / 256, 256, 0, stream>>>(eidx, cursor, eord, E);
    edge_stream_kernel<<<(E + EPB - 1) / EPB, 128, 0, stream>>>(eord, eidx, rbf, cut,
                                                                evec, Wr, br, P3,
                                                                ds, dv, E);
}

// Round 8
// 318.641 us; speedup vs baseline: 1.1590x; 1.0035x over previous
//
#include <hip/hip_runtime.h>
#include <hip/hip_bf16.h>

#define HDIM 128
#define H3   384
#define RDIM 20
#define NPB  16   // nodes per block (node MLP)
#define EPB  64   // edges per block (edge stream kernel)

typedef unsigned short u16;
typedef unsigned int   u32;

__device__ __forceinline__ u16 f2bf(float f) {
    __hip_bfloat16 h = __float2bfloat16(f);   // RNE
    return *(u16*)&h;
}
__device__ __forceinline__ float bflo(u32 u) {
    union { u32 i; float f; } x; x.i = u << 16; return x.f;
}
__device__ __forceinline__ float bfhi(u32 u) {
    union { u32 i; float f; } x; x.i = u & 0xffff0000u; return x.f;
}
__device__ __forceinline__ u32 pk(float lo, float hi) {
    return (u32)f2bf(lo) | ((u32)f2bf(hi) << 16);
}

// -------- Kernel 1: per-node MLP -> packed bf16 P3[node][3][128]; fuses v conv --------
__global__ __launch_bounds__(128) void node_mlp_kernel(
    const float* __restrict__ s, const float* __restrict__ W1,
    const float* __restrict__ b1, const float* __restrict__ W2,
    const float* __restrict__ b2, const float* __restrict__ v,
    u32* __restrict__ P3, int N)
{
    __shared__ float sS[NPB][HDIM];
    __shared__ float sH[NPB][HDIM];
    const int t  = threadIdx.x;
    const int n0 = blockIdx.x * NPB;

    #pragma unroll
    for (int n = 0; n < NPB; ++n) {
        int node = n0 + n;
        sS[n][t] = (node < N) ? s[(size_t)node * HDIM + t] : 0.f;
    }
    __syncthreads();

    float acc[NPB];
    #pragma unroll
    for (int n = 0; n < NPB; ++n) acc[n] = 0.f;
    for (int k = 0; k < HDIM; ++k) {
        float w = W1[k * HDIM + t];
        #pragma unroll
        for (int n = 0; n < NPB; ++n) acc[n] += sS[n][k] * w;
    }
    float bb = b1[t];
    #pragma unroll
    for (int n = 0; n < NPB; ++n) {
        float z = acc[n] + bb;
        sH[n][t] = z / (1.f + __expf(-z));   // silu
    }
    __syncthreads();

    float a0[NPB], a1[NPB], a2[NPB];
    #pragma unroll
    for (int n = 0; n < NPB; ++n) { a0[n] = 0.f; a1[n] = 0.f; a2[n] = 0.f; }
    for (int k2 = 0; k2 < HDIM / 2; ++k2) {
        float2 hv[NPB];
        #pragma unroll
        for (int n = 0; n < NPB; ++n) hv[n] = ((const float2*)sH[n])[k2];
        #pragma unroll
        for (int kk = 0; kk < 2; ++kk) {
            int k = 2 * k2 + kk;
            float w0 = W2[k * H3 + t];
            float w1 = W2[k * H3 + t + 128];
            float w2 = W2[k * H3 + t + 256];
            #pragma unroll
            for (int n = 0; n < NPB; ++n) {
                float h = kk ? hv[n].y : hv[n].x;
                a0[n] += h * w0;
                a1[n] += h * w1;
                a2[n] += h * w2;
            }
        }
    }
    float c0 = b2[t], c1 = b2[t + 128], c2 = b2[t + 256];
    #pragma unroll
    for (int n = 0; n < NPB; ++n) {
        int node = n0 + n;
        if (node < N) {
            size_t vb = (size_t)node * H3;
            float vx = v[vb + t], vy = v[vb + 128 + t], vz = v[vb + 256 + t];
            size_t pb = (size_t)node * H3 + t;
            P3[pb]       = pk(a0[n] + c0, a1[n] + c1);   // (pss, psv)
            P3[pb + 128] = pk(a2[n] + c2, vx);           // (pvv, vx)
            P3[pb + 256] = pk(vy, vz);                   // (vy, vz)
        }
    }
}

// -------- CSR build (sort edges by destination) --------
__global__ void hist_kernel(const int* __restrict__ eidx, int* __restrict__ counts, int E)
{
    int e = blockIdx.x * 256 + threadIdx.x;
    if (e < E) atomicAdd(&counts[eidx[e]], 1);
}

__global__ __launch_bounds__(1024) void scan_kernel(
    const int* __restrict__ counts, int* __restrict__ rstart,
    int* __restrict__ cursor, int N)
{
    __shared__ int part[1024];
    const int t = threadIdx.x;
    const int C = 20;
    int loc[C];
    int s = 0;
    #pragma unroll
    for (int q = 0; q < C; ++q) {
        int idx = t * C + q;
        int c = (idx < N) ? counts[idx] : 0;
        loc[q] = s; s += c;
    }
    part[t] = s;
    __syncthreads();
    for (int off = 1; off < 1024; off <<= 1) {
        int vv = (t >= off) ? part[t - off] : 0;
        __syncthreads();
        part[t] += vv;
        __syncthreads();
    }
    int boff = (t > 0) ? part[t - 1] : 0;
    #pragma unroll
    for (int q = 0; q < C; ++q) {
        int idx = t * C + q;
        if (idx < N) {
            int st = boff + loc[q];
            rstart[idx] = st;
            cursor[idx] = st;
        }
    }
    if (t == 1023) rstart[N] = part[1023];
}

__global__ void scatter_kernel(const int* __restrict__ eidx, int* __restrict__ cursor,
                               int* __restrict__ eord, int E)
{
    int e = blockIdx.x * 256 + threadIdx.x;
    if (e < E) {
        int i = eidx[e];
        int pos = atomicAdd(&cursor[i], 1);
        eord[pos] = e;
    }
}

// -------- Kernel 2: edge-centric streaming over destination-sorted edges --------
__global__ __launch_bounds__(128, 4) void edge_stream_kernel(
    const int* __restrict__ eord, const int* __restrict__ eidx,
    const float* __restrict__ rbf, const float* __restrict__ cutoff,
    const float* __restrict__ evec, const float* __restrict__ Wr,
    const float* __restrict__ br, const u32* __restrict__ P3,
    float* __restrict__ ds, float* __restrict__ dv, int E)
{
    const int t    = threadIdx.x;
    const int base = blockIdx.x * EPB;
    const int cnt  = min(EPB, E - base);

    // Wr columns for this thread's 3 output columns, loaded ONCE.
    // asm pin: after this, values are not provably equal to memory, so the
    // compiler cannot rematerialize the loads inside the edge loop — they
    // must stay resident in VGPRs (r7 showed VGPR=52 => they were reloaded).
    float wr[3 * RDIM];
    #pragma unroll
    for (int k = 0; k < RDIM; ++k) {
        wr[k]            = Wr[k * H3 + t];
        wr[RDIM + k]     = Wr[k * H3 + t + 128];
        wr[2 * RDIM + k] = Wr[k * H3 + t + 256];
    }
    float br0 = br[t], br1 = br[t + 128], br2 = br[t + 256];
    #pragma unroll
    for (int k = 0; k < 3 * RDIM; ++k) asm volatile("" : "+v"(wr[k]));
    asm volatile("" : "+v"(br0), "+v"(br1), "+v"(br2));

    __shared__ int   sI[EPB], sJ[EPB];
    __shared__ float sCut[EPB], sVx[EPB], sVy[EPB], sVz[EPB];
    __shared__ __attribute__((aligned(16))) float sRbf[EPB][RDIM];

    if (t < cnt) {
        int e   = eord[base + t];
        sI[t]   = eidx[e];
        sJ[t]   = eidx[E + e] * H3;
        sCut[t] = cutoff[e];
        sVx[t]  = evec[3 * e];
        sVy[t]  = evec[3 * e + 1];
        sVz[t]  = evec[3 * e + 2];
        // stage this edge's rbf row (80 B) as 5 x float4
        const float4* rr = (const float4*)(rbf + (size_t)e * RDIM);
        float4* dst = (float4*)sRbf[t];
        #pragma unroll
        for (int j = 0; j < 5; ++j) dst[j] = rr[j];
    }
    __syncthreads();

    // depth-1 prefetch of the 3 packed gather words
    u32 ca, cb, cc;
    {
        int idx = sJ[0] + t;
        ca = P3[idx]; cb = P3[idx + 128]; cc = P3[idx + 256];
    }
    int   cur  = sI[0];
    float accs = 0.f, accx = 0.f, accy = 0.f, accz = 0.f;

    for (int q = 0; q < cnt; ++q) {
        u32 na = 0, nb = 0, nc = 0;
        if (q + 1 < cnt) {
            int idx = sJ[q + 1] + t;
            na = P3[idx]; nb = P3[idx + 128]; nc = P3[idx + 256];
        }
        int iq = sI[q];                    // uniform across block
        if (iq != cur) {                   // run boundary: flush (uniform branch)
            atomicAdd(&ds[(size_t)cur * HDIM + t], accs);
            size_t dvi = (size_t)cur * H3;
            atomicAdd(&dv[dvi + t],       accx);
            atomicAdd(&dv[dvi + 128 + t], accy);
            atomicAdd(&dv[dvi + 256 + t], accz);
            accs = accx = accy = accz = 0.f;
            cur = iq;
        }
        const float4* r4 = (const float4*)sRbf[q];
        float w0 = 0.f, w1 = 0.f, w2 = 0.f;
        #pragma unroll
        for (int k4 = 0; k4 < 5; ++k4) {
            float4 r = r4[k4];
            w0 += r.x * wr[4*k4]          + r.y * wr[4*k4+1]          + r.z * wr[4*k4+2]          + r.w * wr[4*k4+3];
            w1 += r.x * wr[RDIM+4*k4]     + r.y * wr[RDIM+4*k4+1]     + r.z * wr[RDIM+4*k4+2]     + r.w * wr[RDIM+4*k4+3];
            w2 += r.x * wr[2*RDIM+4*k4]   + r.y * wr[2*RDIM+4*k4+1]   + r.z * wr[2*RDIM+4*k4+2]   + r.w * wr[2*RDIM+4*k4+3];
        }
        float cu = sCut[q];
        float ex = sVx[q], ey = sVy[q], ez = sVz[q];
        float pss = bflo(ca), psv = bfhi(ca);
        float pvv = bflo(cb), vx  = bfhi(cb);
        float vy  = bflo(cc), vz  = bfhi(cc);
        float xss = (w0 + br0) * cu * pss;
        float xsv = (w1 + br1) * cu * psv;
        float xvv = (w2 + br2) * cu * pvv;
        float inner = vx * ex + vy * ey + vz * ez;
        float coef  = xsv + inner * xvv;
        accs += xss;
        accx += coef * ex;
        accy += coef * ey;
        accz += coef * ez;
        ca = na; cb = nb; cc = nc;
    }
    // final flush
    atomicAdd(&ds[(size_t)cur * HDIM + t], accs);
    size_t dvi = (size_t)cur * H3;
    atomicAdd(&dv[dvi + t],       accx);
    atomicAdd(&dv[dvi + 128 + t], accy);
    atomicAdd(&dv[dvi + 256 + t], accz);
}

extern "C" void kernel_launch(void* const* d_in, const int* in_sizes, int n_in,
                              void* d_out, int out_size, void* d_ws, size_t ws_size,
                              hipStream_t stream)
{
    const float* s    = (const float*)d_in[0];
    const float* v    = (const float*)d_in[1];
    const float* rbf  = (const float*)d_in[2];
    const float* cut  = (const float*)d_in[3];
    const float* evec = (const float*)d_in[4];
    const float* W1   = (const float*)d_in[5];
    const float* b1   = (const float*)d_in[6];
    const float* W2   = (const float*)d_in[7];
    const float* b2   = (const float*)d_in[8];
    const float* Wr   = (const float*)d_in[9];
    const float* br   = (const float*)d_in[10];
    const int*   eidx = (const int*)d_in[11];

    const int N = in_sizes[0] / HDIM;   // 20000
    const int E = in_sizes[3];          // 400000

    float* out = (float*)d_out;
    float* ds  = out;                      // [N, H]
    float* dv  = out + (size_t)N * HDIM;   // [N, 3, H]

    // workspace layout (256B aligned chunks)
    char* w = (char*)d_ws;
    u32* P3 = (u32*)w;                     w += ((size_t)N * H3 * 4 + 255) / 256 * 256;
    int* counts = (int*)w;                 w += ((size_t)N * 4 + 255) / 256 * 256;
    int* rstart = (int*)w;                 w += ((size_t)(N + 1) * 4 + 255) / 256 * 256;
    int* cursor = (int*)w;                 w += ((size_t)N * 4 + 255) / 256 * 256;
    int* eord   = (int*)w;

    hipMemsetAsync(d_out, 0, (size_t)out_size * sizeof(float), stream);
    hipMemsetAsync(counts, 0, (size_t)N * sizeof(int), stream);

    node_mlp_kernel<<<(N + NPB - 1) / NPB, 128, 0, stream>>>(s, W1, b1, W2, b2, v, P3, N);
    hist_kernel<<<(E + 255) / 256, 256, 0, stream>>>(eidx, counts, E);
    scan_kernel<<<1, 1024, 0, stream>>>(counts, rstart, cursor, N);
    scatter_kernel<<<(E + 255) / 256, 256, 0, stream>>>(eidx, cursor, eord, E);
    edge_stream_kernel<<<(E + EPB - 1) / EPB, 128, 0, stream>>>(eord, eidx, rbf, cut,
                                                                evec, Wr, br, P3,
                                                                ds, dv, E);
}